// Round 1
// baseline (918.454 us; speedup 1.0000x reference)
//
#include <hip/hip_runtime.h>
#include <hip/hip_bf16.h>

// InteractionBlock: per-edge radial MLP (8->64->64->768) + tensor product
// contraction + scatter-sum + self-interaction + batchnorm epilogue.
// Round 12: occupancy attack. Evidence: Occupancy 10.5% (~3.4 waves/CU) with
// MfmaUtil 6.3% / VALUBusy 19% / HBM 3.9% -- latency-bound from wave scarcity.
// 1-wave workgroups hit the per-SE workgroup-slot cap (~4 WG/CU), not VGPR/LDS.
// (a) 256-thread blocks = 4 fully independent waves, per-wave LDS slices
//     (50176 B/block, 2 blocks/CU; VGPR bracket allows 8 waves/CU);
// (b) __syncthreads -> per-wave s_waitcnt lgkmcnt(0) fences (waves never
//     lockstep; LDS is wave-private);
// (c) h2 LDS writes paired into u32 (32x ds_write_b32 vs 64x b16 at the
//     8-way-conflicted 144B stride).

#define N_NODES_C 50000
#define N_EDGES_C 300000
#define ALPHA_C 0.20412414523193154f   // 1/sqrt(24)
#define INV_SQRT3_C 0.5773502691896258f
#define BN_EPS_C 1e-5f

typedef unsigned int u32;
typedef unsigned long long u64;
typedef unsigned short u16;
typedef __attribute__((ext_vector_type(8))) short bf16x8;
typedef __attribute__((ext_vector_type(4))) float f32x4;

// workspace layout (float offsets)
#define OFF_STATS 0u            // 40
#define OFF_FLAG  48u           // u32 dtype flag
#define OFF_W3T   64u           // 49152 floats: frag-packed W3 bf16 hi + lo
#define OFF_W1T   49216u        // 512
#define OFF_B1    49728u        // 64
#define OFF_W2T   49792u        // 4096
#define OFF_B2    53888u        // 64
#define OFF_B3    53952u        // 768
#define OFF_SI0   54720u        // 256
#define OFF_SI1   54976u        // 64
#define OFF_AGG   55040u        // 50000*48 = 2,400,000 (svb in-place)
#define REQ_WS_BYTES ((size_t)(55040u + 2400000u) * 4u)
// sorted-path extras
#define OFF_DEG     2455040u    // 50000 ints
#define OFF_START   2505040u    // 50001 ints
#define OFF_CURSOR  2555044u    // 50000 ints
#define OFF_POS     2605044u    // 300000 ints (inverse perm: edge -> sorted slot)
#define OFF_MSG     2905044u    // 300000*48 floats (16B aligned)
#define REQ2_WS_BYTES ((size_t)(2905044u + 14400000u) * 4u)   // ~69.2 MB

__device__ __forceinline__ float bflo(u32 u){ union{u32 i; float f;} c; c.i = u<<16; return c.f; }
__device__ __forceinline__ float bfhi(u32 u){ union{u32 i; float f;} c; c.i = u & 0xffff0000u; return c.f; }
__device__ __forceinline__ float b2f(__hip_bfloat16 b){ return (float)b; }
__device__ __forceinline__ u16 f2bf(float f){
    union{float f; u32 i;} c; c.f = f;
    u32 r = c.i + 0x7fffu + ((c.i>>16)&1u);
    return (u16)(r>>16);
}
__device__ __forceinline__ float sigmoidf_(float x){ return 1.0f/(1.0f+__expf(-x)); }
__device__ __forceinline__ float siluf_(float x){ return x*sigmoidf_(x); }
__device__ __forceinline__ float rdv(const void* p, int idx, bool fm){
    return fm ? ((const float*)p)[idx] : b2f(((const __hip_bfloat16*)p)[idx]);
}
__device__ __forceinline__ float sel4(float a, float b, float c, float d, int q){
    float lo = (q&1) ? b : a;
    float hi = (q&1) ? d : c;
    return (q&2) ? hi : lo;
}
__device__ __forceinline__ float sel8(float a0,float a1,float a2,float a3,
                                      float a4,float a5,float a6,float a7,int q){
    float x0=(q&1)?a1:a0, x1=(q&1)?a3:a2, x2=(q&1)?a5:a4, x3=(q&1)?a7:a6;
    float y0=(q&2)?x1:x0, y1=(q&2)?x3:x2;
    return (q&4)?y1:y0;
}
// per-wave LDS fence: wave-private LDS means no cross-wave barrier needed;
// lgkmcnt(0) orders ds_write -> ds_read within the wave. sched_barrier(0)
// prevents hipcc hoisting register-only ops past the inline-asm wait (rule #18).
__device__ __forceinline__ void wave_fence(){
    asm volatile("s_waitcnt lgkmcnt(0)" ::: "memory");
    __builtin_amdgcn_sched_barrier(0);
}

// ---------------- detect dtype ----------------
__global__ void detect_kernel(const u32* __restrict__ nfw, u32* __restrict__ flagp){
    int t = threadIdx.x;
    u32 w = nfw[t];
    int bad = 0;
    u32 lo = w & 0xffffu, hi = w >> 16;
    u32 elo = (lo >> 7) & 0xffu, ehi = (hi >> 7) & 0xffu;
    if (!(lo == 0u || (elo >= 90u && elo <= 140u))) bad++;
    if (!(hi == 0u || (ehi >= 90u && ehi <= 140u))) bad++;
    for (int off=32; off; off>>=1) bad += __shfl_down(bad, off);
    if (t == 0) flagp[0] = (bad >= 8) ? 1u : 0u;
}

__global__ __launch_bounds__(256) void fill_kernel(u32* __restrict__ p, int n, u32 v){
    int i = blockIdx.x*256 + threadIdx.x;
    if (i < n) p[i] = v;
}

// ---------------- prep ----------------
__global__ __launch_bounds__(256) void prep_kernel(
    const void* __restrict__ W1, const void* __restrict__ b1,
    const void* __restrict__ W2, const void* __restrict__ b2,
    const void* __restrict__ W3, const void* __restrict__ b3,
    const void* __restrict__ si0, const void* __restrict__ si1,
    float* __restrict__ ws)
{
    const bool fm = ((const u32*)(ws + OFF_FLAG))[0] != 0u;
    int i = blockIdx.x*256 + threadIdx.x;
    if (i < 49152){
        int j = i & 7, lane = (i>>3)&63, kh = (i>>9)&1, nt = i>>10;
        int n = lane & 15, qd = lane >> 4;
        int k = kh*32 + qd*8 + j;
        int col = nt*16 + n;
        float v = rdv(W3, k*768 + col, fm);
        u16 hv = f2bf(v);
        float hf = bflo((u32)hv);
        u16 lv = f2bf(v - hf);
        u16* BH = (u16*)(ws + OFF_W3T);
        BH[i] = hv;
        BH[49152 + i] = lv;
        return;
    }
    i -= 49152;
    if (i < 512){ int j=i>>3, t=i&7; ws[OFF_W1T+i] = rdv(W1, t*64+j, fm); return; }
    i -= 512;
    if (i < 64){ ws[OFF_B1+i] = rdv(b1, i, fm); return; }
    i -= 64;
    if (i < 4096){ int j=i>>6, k=i&63; ws[OFF_W2T+i] = rdv(W2, k*64+j, fm); return; }
    i -= 4096;
    if (i < 64){ ws[OFF_B2+i] = rdv(b2, i, fm); return; }
    i -= 64;
    if (i < 768){ ws[OFF_B3+i] = rdv(b3, i, fm); return; }
    i -= 768;
    if (i < 256){ int w=i>>4, u=i&15; ws[OFF_SI0+i] = rdv(si0, u*16+w, fm)*0.25f; return; }
    i -= 256;
    if (i < 64){ int w=i>>3, u=i&7; ws[OFF_SI1+i] = rdv(si1, u*8+w, fm)*0.35355339059327373f; return; }
}

// ---------------- sort: count / scan / pos-scatter ----------------
__global__ __launch_bounds__(256) void count_kernel(const int* __restrict__ dst, int* __restrict__ deg){
    int i = blockIdx.x*256 + threadIdx.x;
    if (i < N_EDGES_C) atomicAdd(&deg[dst[i]], 1);
}

__global__ __launch_bounds__(1024) void scan_kernel(const int* __restrict__ deg,
                                                    int* __restrict__ start,
                                                    int* __restrict__ cursor){
    __shared__ int buf[2][1024];
    const int t = threadIdx.x;
    const int c0 = t*49;
    int local = 0;
    #pragma unroll 1
    for (int i=0;i<49;i++){ int idx=c0+i; if (idx<N_NODES_C) local += deg[idx]; }
    buf[0][t] = local;
    __syncthreads();
    int src=0;
    for (int off=1; off<1024; off<<=1){
        int v = buf[src][t];
        if (t>=off) v += buf[src][t-off];
        buf[src^1][t]=v;
        src^=1;
        __syncthreads();
    }
    int off = (t==0)?0:buf[src][t-1];
    #pragma unroll 1
    for (int i=0;i<49;i++){
        int idx=c0+i;
        if (idx<N_NODES_C){ start[idx]=off; cursor[idx]=off; off+=deg[idx]; }
    }
    if (t==0) start[N_NODES_C]=buf[src][1023];
}

__global__ __launch_bounds__(256) void scatter_kernel(const int* __restrict__ dst,
                                                      int* __restrict__ cursor,
                                                      int* __restrict__ pos){
    int i = blockIdx.x*256 + threadIdx.x;
    if (i < N_EDGES_C){
        pos[i] = atomicAdd(&cursor[dst[i]], 1);
    }
}

// ---------------- edge kernel (4 independent waves / block; per-wave LDS) ----------------
template<bool SORTED>
__global__ __launch_bounds__(256) void edge_kernel_t(
    const void* __restrict__ nfv,
    const void* __restrict__ eshv,
    const void* __restrict__ ebv,
    const int* __restrict__ eidx,
    const float* __restrict__ ws,
    const int* __restrict__ pos,
    float* __restrict__ outbuf)      // SORTED: msg[300K][48] ; else: agg[50K][48]
{
    // Per-wave private 12544B slice. union: h2 region (9216 B) is dead once
    // A-fragments are in registers; tpb (12544 B) overlays it.
    __shared__ __align__(16) char uni[4][12544];
    const int wv   = threadIdx.x >> 6;
    const int lane = threadIdx.x & 63;
    u16   (*h2hi)[72] = (u16 (*)[72])uni[wv];   // [64][72]
    float (*tpb)[49]  = (float (*)[49])uni[wv]; // [64][49]

    const bool fm = ((const u32*)(ws + OFF_FLAG))[0] != 0u;
    const int m    = lane & 15;
    const int quad = lane >> 4;
    const int e    = blockIdx.x*256 + threadIdx.x;
    const bool act = e < N_EDGES_C;
    const int slot = (SORTED && act) ? pos[e] : 0;   // early, coalesced

    // ---- inputs (original order: coalesced; verified rounds 3/8/9) ----
    float sh0=0.f, sh1x=0.f, sh1y=0.f, sh1z=0.f;
    float f[40];
    float bas[8];
    #pragma unroll
    for (int i=0;i<40;i++) f[i]=0.f;
    #pragma unroll
    for (int i=0;i<8;i++) bas[i]=0.f;
    if (act){
        const int src = eidx[e];
        if (!fm){
            const u32* p = (const u32*)((const __hip_bfloat16*)eshv + (size_t)e*4);
            u32 a = p[0], b = p[1];
            sh0 = bflo(a); sh1x = bfhi(a); sh1y = bflo(b); sh1z = bfhi(b);
            const uint4* qq = (const uint4*)((const __hip_bfloat16*)nfv + (size_t)src*40);
            #pragma unroll
            for (int i=0;i<5;i++){
                uint4 r = qq[i];
                f[i*8+0]=bflo(r.x); f[i*8+1]=bfhi(r.x);
                f[i*8+2]=bflo(r.y); f[i*8+3]=bfhi(r.y);
                f[i*8+4]=bflo(r.z); f[i*8+5]=bfhi(r.z);
                f[i*8+6]=bflo(r.w); f[i*8+7]=bfhi(r.w);
            }
            uint4 r = *(const uint4*)((const __hip_bfloat16*)ebv + (size_t)e*8);
            bas[0]=bflo(r.x); bas[1]=bfhi(r.x); bas[2]=bflo(r.y); bas[3]=bfhi(r.y);
            bas[4]=bflo(r.z); bas[5]=bfhi(r.z); bas[6]=bflo(r.w); bas[7]=bfhi(r.w);
        } else {
            float4 r = *(const float4*)((const float*)eshv + (size_t)e*4);
            sh0 = r.x; sh1x = r.y; sh1y = r.z; sh1z = r.w;
            const float4* qq = (const float4*)((const float*)nfv + (size_t)src*40);
            #pragma unroll
            for (int i=0;i<10;i++){
                float4 t = qq[i];
                f[i*4+0]=t.x; f[i*4+1]=t.y; f[i*4+2]=t.z; f[i*4+3]=t.w;
            }
            const float4* qb = (const float4*)((const float*)ebv + (size_t)e*8);
            float4 t0 = qb[0], t1 = qb[1];
            bas[0]=t0.x; bas[1]=t0.y; bas[2]=t0.z; bas[3]=t0.w;
            bas[4]=t1.x; bas[5]=t1.y; bas[6]=t1.z; bas[7]=t1.w;
        }
    }

    // ---- MLP1 ----
    const float* W1T = ws + OFF_W1T;
    const float* b1f = ws + OFF_B1;
    float h1[64];
    #pragma unroll
    for (int j=0;j<64;j++){
        const float* w = W1T + j*8;
        float t0 = b1f[j] + bas[0]*w[0] + bas[4]*w[4];
        float t1 = bas[1]*w[1] + bas[5]*w[5];
        float t2 = bas[2]*w[2] + bas[6]*w[6];
        float t3 = bas[3]*w[3] + bas[7]*w[7];
        h1[j] = siluf_((t0+t1)+(t2+t3));
    }

    // ---- MLP2 -> bf16 h2 rows in LDS (paired u32 writes) ----
    const float* W2T = ws + OFF_W2T;
    const float* bb2 = ws + OFF_B2;
    #pragma unroll 1
    for (int j=0;j<64;j+=2){
        const float* w0 = W2T + j*64;
        const float* w1 = w0 + 64;
        float a0=bb2[j],   a1=0.f, a2=0.f, a3=0.f;
        float c0=bb2[j+1], c1=0.f, c2=0.f, c3=0.f;
        #pragma unroll
        for (int k=0;k<64;k+=4){
            a0 += h1[k]*w0[k];     a1 += h1[k+1]*w0[k+1];
            a2 += h1[k+2]*w0[k+2]; a3 += h1[k+3]*w0[k+3];
            c0 += h1[k]*w1[k];     c1 += h1[k+1]*w1[k+1];
            c2 += h1[k+2]*w1[k+2]; c3 += h1[k+3]*w1[k+3];
        }
        u32 pk = (u32)f2bf(siluf_((a0+a1)+(a2+a3)))
               | ((u32)f2bf(siluf_((c0+c1)+(c2+c3)))<<16);
        *(u32*)&h2hi[lane][j] = pk;
    }
    wave_fence();

    // ---- A fragments (consume all of h2 into registers) ----
    bf16x8 Afr[4][2];
    #pragma unroll
    for (int g=0;g<4;g++){
        Afr[g][0] = *(const bf16x8*)&h2hi[g*16+m][quad*8];
        Afr[g][1] = *(const bf16x8*)&h2hi[g*16+m][32 + quad*8];
    }
    wave_fence();   // h2 region now dead -> tpb may overlay

    // ---- per-thread contraction coefficients ----
    float cssx[16], vxsh0[24], dvv[8];
    #pragma unroll
    for (int u=0;u<16;u++) cssx[u] = f[u]*sh0;
    #pragma unroll
    for (int j=0;j<24;j++) vxsh0[j] = f[16+j]*sh0;
    #pragma unroll
    for (int u=0;u<8;u++)
        dvv[u] = (f[16+u*3]*sh1x + f[17+u*3]*sh1y + f[18+u*3]*sh1z)*INV_SQRT3_C;

    float outs[24], tsv[8], av0[8], av1[8], av2[8];
    #pragma unroll
    for (int t=0;t<24;t++) outs[t]=0.f;
    #pragma unroll
    for (int t=0;t<8;t++){ tsv[t]=0.f; av0[t]=0.f; av1[t]=0.f; av2[t]=0.f; }

    const short* BH = (const short*)(ws + OFF_W3T);
    const short* BL = BH + 49152;
    const float* b3f = ws + OFF_B3;

    auto loadB = [&](bf16x8* dst2, int cc2){
        #pragma unroll
        for (int ntl=0; ntl<3; ntl++){
            const int nt = cc2*3 + ntl;
            dst2[ntl*4+0] = *(const bf16x8*)(BH + ((nt*2+0)*64 + lane)*8);
            dst2[ntl*4+1] = *(const bf16x8*)(BL + ((nt*2+0)*64 + lane)*8);
            dst2[ntl*4+2] = *(const bf16x8*)(BH + ((nt*2+1)*64 + lane)*8);
            dst2[ntl*4+3] = *(const bf16x8*)(BL + ((nt*2+1)*64 + lane)*8);
        }
    };

    bf16x8 Bcur[12], Bnxt[12];
    loadB(Bcur, 0);

    #pragma unroll 1
    for (int cc=0; cc<16; cc++){
        if (cc < 15) loadB(Bnxt, cc+1);

        #pragma unroll
        for (int ntl=0; ntl<3; ntl++){
            #pragma unroll
            for (int g=0; g<4; g++){
                f32x4 acc = {0.f,0.f,0.f,0.f};
                acc = __builtin_amdgcn_mfma_f32_16x16x32_bf16(Afr[g][0], Bcur[ntl*4+0], acc, 0,0,0);
                acc = __builtin_amdgcn_mfma_f32_16x16x32_bf16(Afr[g][0], Bcur[ntl*4+1], acc, 0,0,0);
                acc = __builtin_amdgcn_mfma_f32_16x16x32_bf16(Afr[g][1], Bcur[ntl*4+2], acc, 0,0,0);
                acc = __builtin_amdgcn_mfma_f32_16x16x32_bf16(Afr[g][1], Bcur[ntl*4+3], acc, 0,0,0);
                #pragma unroll
                for (int r=0;r<4;r++) tpb[g*16+quad*4+r][ntl*16+m] = acc[r];
            }
        }
        wave_fence();

        float vals[48];
        #pragma unroll
        for (int c=0;c<48;c++) vals[c] = tpb[lane][c] + b3f[cc*48+c];

        if (cc < 8){
            float cA = sel8(cssx[0],cssx[2],cssx[4],cssx[6],cssx[8],cssx[10],cssx[12],cssx[14], cc);
            float cB = sel8(cssx[1],cssx[3],cssx[5],cssx[7],cssx[9],cssx[11],cssx[13],cssx[15], cc);
            #pragma unroll
            for (int c=0;c<24;c++) outs[c] += cA*vals[c];
            #pragma unroll
            for (int c=0;c<24;c++) outs[c] += cB*vals[24+c];
        } else if (cc < 12){
            int q = cc-8;
            float cA = sel4(dvv[0],dvv[2],dvv[4],dvv[6], q);
            float cB = sel4(dvv[1],dvv[3],dvv[5],dvv[7], q);
            #pragma unroll
            for (int c=0;c<24;c++) outs[c] += cA*vals[c];
            #pragma unroll
            for (int c=0;c<24;c++) outs[c] += cB*vals[24+c];
        } else if (cc == 12){
            #pragma unroll
            for (int c=0;c<48;c++) tsv[c&7] += f[c>>3]*vals[c];
        } else if (cc == 13){
            #pragma unroll
            for (int c=0;c<48;c++) tsv[c&7] += f[6+(c>>3)]*vals[c];
        } else if (cc == 14){
            #pragma unroll
            for (int c=0;c<32;c++) tsv[c&7] += f[12+(c>>3)]*vals[c];
            #pragma unroll
            for (int c=32;c<48;c++){
                const int u=(c-32)>>3, w=(c-32)&7;
                av0[w] += vxsh0[u*3+0]*vals[c];
                av1[w] += vxsh0[u*3+1]*vals[c];
                av2[w] += vxsh0[u*3+2]*vals[c];
            }
        } else {
            #pragma unroll
            for (int c=0;c<48;c++){
                const int u=2+(c>>3), w=c&7;
                av0[w] += vxsh0[u*3+0]*vals[c];
                av1[w] += vxsh0[u*3+1]*vals[c];
                av2[w] += vxsh0[u*3+2]*vals[c];
            }
        }
        wave_fence();

        #pragma unroll
        for (int i=0;i<12;i++) Bcur[i] = Bnxt[i];
    }

    if (act){
        if (SORTED){
            // scattered full-line stores to msg[slot][48]
            float v48[48];
            #pragma unroll
            for (int w=0;w<24;w++) v48[w] = outs[w]*ALPHA_C;
            #pragma unroll
            for (int w=0;w<8;w++){
                v48[24+w*3+0] = (tsv[w]*sh1x + av0[w])*ALPHA_C;
                v48[24+w*3+1] = (tsv[w]*sh1y + av1[w])*ALPHA_C;
                v48[24+w*3+2] = (tsv[w]*sh1z + av2[w])*ALPHA_C;
            }
            float4* mp = (float4*)(outbuf + (size_t)slot*48);
            #pragma unroll
            for (int q=0;q<12;q++) mp[q] = make_float4(v48[q*4],v48[q*4+1],v48[q*4+2],v48[q*4+3]);
        } else {
            const int dst = eidx[N_EDGES_C + e];
            float* dp = outbuf + (size_t)dst*48;
            #pragma unroll
            for (int w=0;w<24;w++) atomicAdd(dp+w, outs[w]*ALPHA_C);
            #pragma unroll
            for (int w=0;w<8;w++){
                atomicAdd(dp+24+w*3+0, (tsv[w]*sh1x + av0[w])*ALPHA_C);
                atomicAdd(dp+24+w*3+1, (tsv[w]*sh1y + av1[w])*ALPHA_C);
                atomicAdd(dp+24+w*3+2, (tsv[w]*sh1z + av2[w])*ALPHA_C);
            }
        }
    }
}

// ---------------- node kernel (templated source of agg) ----------------
template<bool SORTED>
__global__ __launch_bounds__(256) void node_kernel_t(
    const float* __restrict__ ws,
    const float* __restrict__ msg,     // SORTED only
    const int* __restrict__ start,     // SORTED only
    float* __restrict__ svb,           // agg region: read (atomic path) / write svb
    float* __restrict__ stats)
{
    const float* si0T = ws + OFF_SI0;
    const float* si1T = ws + OFF_SI1;
    const int n = blockIdx.x*256 + threadIdx.x;
    const bool act = n < N_NODES_C;

    float a[48];
    #pragma unroll
    for (int j=0;j<48;j++) a[j]=0.f;
    if (act){
        if (SORTED){
            int s = start[n], en = start[n+1];
            #pragma unroll 1
            for (int r=s; r<en; ++r){
                const float4* mp = (const float4*)(msg + (size_t)r*48);
                #pragma unroll
                for (int q=0;q<12;q++){
                    float4 t = mp[q];
                    a[q*4]+=t.x; a[q*4+1]+=t.y; a[q*4+2]+=t.z; a[q*4+3]+=t.w;
                }
            }
        } else {
            const float4* p = (const float4*)(svb + (size_t)n*48);
            #pragma unroll
            for (int q=0;q<12;q++){ float4 r=p[q]; a[q*4]=r.x; a[q*4+1]=r.y; a[q*4+2]=r.z; a[q*4+3]=r.w; }
        }
    }
    float spre[16];
    #pragma unroll
    for (int u=0;u<16;u++) spre[u]=siluf_(a[u]);
    float v[24];
    #pragma unroll
    for (int u=0;u<8;u++){
        float g = sigmoidf_(a[16+u]);
        v[u*3+0]=a[24+u*3+0]*g; v[u*3+1]=a[24+u*3+1]*g; v[u*3+2]=a[24+u*3+2]*g;
    }
    float so[16];
    #pragma unroll
    for (int w=0;w<16;w++){
        const float* c = si0T + w*16;
        float t0=0.f,t1=0.f,t2=0.f,t3=0.f;
        #pragma unroll
        for (int u=0;u<16;u+=4){ t0+=spre[u]*c[u]; t1+=spre[u+1]*c[u+1]; t2+=spre[u+2]*c[u+2]; t3+=spre[u+3]*c[u+3]; }
        so[w]=(t0+t1)+(t2+t3);
    }
    float vo[24];
    #pragma unroll
    for (int w=0;w<8;w++){
        const float* c = si1T + w*8;
        float a0=0.f,a1=0.f,a2=0.f;
        #pragma unroll
        for (int u=0;u<8;u++){ a0+=v[u*3]*c[u]; a1+=v[u*3+1]*c[u]; a2+=v[u*3+2]*c[u]; }
        vo[w*3]=a0; vo[w*3+1]=a1; vo[w*3+2]=a2;
    }
    if (act){
        float4* op = (float4*)(svb + (size_t)n*48);
        op[0]=make_float4(so[0],so[1],so[2],so[3]);
        op[1]=make_float4(so[4],so[5],so[6],so[7]);
        op[2]=make_float4(so[8],so[9],so[10],so[11]);
        op[3]=make_float4(so[12],so[13],so[14],so[15]);
        #pragma unroll
        for (int q=0;q<6;q++) op[4+q]=make_float4(vo[q*4],vo[q*4+1],vo[q*4+2],vo[q*4+3]);
    }
    float r[40];
    #pragma unroll
    for (int w=0;w<16;w++){ r[w]=so[w]; r[16+w]=so[w]*so[w]; }
    #pragma unroll
    for (int w=0;w<8;w++) r[32+w]=(vo[w*3]*vo[w*3]+vo[w*3+1]*vo[w*3+1]+vo[w*3+2]*vo[w*3+2])*(1.0f/3.0f);
    #pragma unroll
    for (int j=0;j<40;j++){
        float x = r[j];
        for (int off=32; off; off>>=1) x += __shfl_down(x, off);
        r[j]=x;
    }
    if ((threadIdx.x & 63)==0){
        #pragma unroll
        for (int j=0;j<40;j++) atomicAdd(stats+j, r[j]);
    }
}

// ---------------- finalize ----------------
__global__ __launch_bounds__(256) void final_kernel(
    const float* __restrict__ ws, const float* __restrict__ svb,
    const void* __restrict__ nfv,
    const void* __restrict__ bnws, const void* __restrict__ bnbs,
    const void* __restrict__ bnwv,
    void* __restrict__ outv)
{
    const float* stats = ws + OFF_STATS;
    const bool fm = ((const u32*)(ws + OFF_FLAG))[0] != 0u;
    const int n = blockIdx.x*256 + threadIdx.x;
    if (n >= N_NODES_C) return;
    const float invN = 1.0f/(float)N_NODES_C;
    const float* s = svb + (size_t)n*48;
    float nfr[40];
    if (!fm){
        const uint4* q = (const uint4*)((const __hip_bfloat16*)nfv + (size_t)n*40);
        #pragma unroll
        for (int i=0;i<5;i++){
            uint4 r = q[i];
            nfr[i*8+0]=bflo(r.x); nfr[i*8+1]=bfhi(r.x);
            nfr[i*8+2]=bflo(r.y); nfr[i*8+3]=bfhi(r.y);
            nfr[i*8+4]=bflo(r.z); nfr[i*8+5]=bfhi(r.z);
            nfr[i*8+6]=bflo(r.w); nfr[i*8+7]=bfhi(r.w);
        }
    } else {
        const float4* q = (const float4*)((const float*)nfv + (size_t)n*40);
        #pragma unroll
        for (int i=0;i<10;i++){
            float4 t = q[i];
            nfr[i*4+0]=t.x; nfr[i*4+1]=t.y; nfr[i*4+2]=t.z; nfr[i*4+3]=t.w;
        }
    }
    float vals[40];
    #pragma unroll
    for (int w=0;w<16;w++){
        float mean = stats[w]*invN;
        float var  = fmaxf(stats[16+w]*invN - mean*mean, 0.0f);
        float is   = rsqrtf(var + BN_EPS_C) * rdv(bnws, w, fm);
        vals[w] = (s[w]-mean)*is + rdv(bnbs, w, fm) + nfr[w];
    }
    #pragma unroll
    for (int w=0;w<8;w++){
        float iv = rsqrtf(fmaxf(stats[32+w]*invN, 0.0f) + BN_EPS_C) * rdv(bnwv, w, fm);
        vals[16+w*3+0] = s[16+w*3+0]*iv + nfr[16+w*3+0];
        vals[16+w*3+1] = s[16+w*3+1]*iv + nfr[16+w*3+1];
        vals[16+w*3+2] = s[16+w*3+2]*iv + nfr[16+w*3+2];
    }
    if (!fm){
        u32 packed[20];
        #pragma unroll
        for (int q=0;q<20;q++) packed[q] = (u32)f2bf(vals[2*q]) | ((u32)f2bf(vals[2*q+1])<<16);
        uint4* op = (uint4*)((u16*)outv + (size_t)n*40);
        #pragma unroll
        for (int q=0;q<5;q++) op[q] = make_uint4(packed[q*4],packed[q*4+1],packed[q*4+2],packed[q*4+3]);
    } else {
        float4* op = (float4*)((float*)outv + (size_t)n*40);
        #pragma unroll
        for (int q=0;q<10;q++) op[q] = make_float4(vals[q*4],vals[q*4+1],vals[q*4+2],vals[q*4+3]);
    }
}

extern "C" void kernel_launch(void* const* d_in, const int* in_sizes, int n_in,
                              void* d_out, int out_size, void* d_ws, size_t ws_size,
                              hipStream_t stream)
{
    const void* nf     = d_in[0];
    const void* esh    = d_in[1];
    const void* ebasis = d_in[2];
    const int*  eidx   = (const int*)d_in[3];
    const void* W1 = d_in[4];
    const void* b1 = d_in[5];
    const void* W2 = d_in[6];
    const void* b2 = d_in[7];
    const void* W3 = d_in[8];
    const void* b3 = d_in[9];
    const void* si0 = d_in[10];
    const void* si1 = d_in[11];
    const void* bnws = d_in[12];
    const void* bnbs = d_in[13];
    const void* bnwv = d_in[14];

    float* ws    = (float*)d_ws;
    float* stats = ws + OFF_STATS;
    float* agg   = ws + OFF_AGG;

    if (ws_size < REQ_WS_BYTES){
        int nw = out_size/2;
        fill_kernel<<<(nw+255)/256, 256, 0, stream>>>((u32*)d_out, nw, 0x447A447Au);
        return;
    }

    const int* dst = eidx + N_EDGES_C;
    const int EB = (N_EDGES_C+255)/256;

    hipMemsetAsync(stats, 0, 48*sizeof(float), stream);
    detect_kernel<<<1, 64, 0, stream>>>((const u32*)nf, (u32*)(ws + OFF_FLAG));
    prep_kernel<<<215, 256, 0, stream>>>(W1,b1,W2,b2,W3,b3,si0,si1, ws);

    if (ws_size >= REQ2_WS_BYTES){
        // ---- sorted (atomic-free aggregation) path ----
        int*   deg    = (int*)(ws + OFF_DEG);
        int*   startp = (int*)(ws + OFF_START);
        int*   cursor = (int*)(ws + OFF_CURSOR);
        int*   pos    = (int*)(ws + OFF_POS);
        float* msg    = ws + OFF_MSG;

        hipMemsetAsync(deg, 0, N_NODES_C*sizeof(int), stream);
        count_kernel<<<EB, 256, 0, stream>>>(dst, deg);
        scan_kernel<<<1, 1024, 0, stream>>>(deg, startp, cursor);
        scatter_kernel<<<EB, 256, 0, stream>>>(dst, cursor, pos);
        edge_kernel_t<true><<<(N_EDGES_C+255)/256, 256, 0, stream>>>(nf, esh, ebasis, eidx, ws, pos, msg);
        node_kernel_t<true><<<(N_NODES_C+255)/256, 256, 0, stream>>>(ws, msg, startp, agg, stats);
    } else {
        // ---- fallback: atomic path ----
        hipMemsetAsync(agg, 0, (size_t)2400000*sizeof(float), stream);
        edge_kernel_t<false><<<(N_EDGES_C+255)/256, 256, 0, stream>>>(nf, esh, ebasis, eidx, ws, nullptr, agg);
        node_kernel_t<false><<<(N_NODES_C+255)/256, 256, 0, stream>>>(ws, nullptr, nullptr, agg, stats);
    }
    final_kernel<<<(N_NODES_C+255)/256, 256, 0, stream>>>(ws, agg, nf, bnws, bnbs, bnwv, d_out);
}

// Round 2
// 772.696 us; speedup vs baseline: 1.1886x; 1.1886x over previous
//
#include <hip/hip_runtime.h>
#include <hip/hip_bf16.h>

// InteractionBlock: per-edge radial MLP (8->64->64->768) + tensor product
// contraction + scatter-sum + self-interaction + batchnorm epilogue.
// Round 13: register-cliff attack. r11/r12 both pinned at Occupancy ~10.5%
// (= 12.5% cap = 1 wave/SIMD) independent of block shape => unified
// VGPR+accVGPR budget > 256 was the limiter (196 arch VGPR + acc regs).
// (a) single B buffer (-48 VGPR): issue next B-loads right after MFMAs
//     consume current B; lgkmcnt-only fences keep vmcnt outstanding so the
//     loads overlap the contraction VALU phase (same prefetch distance);
// (b) vals[48] -> 3 chunks of 16 (-32 peak VGPR), identical FP order;
// (c) cssx[] dropped, cA/cB recomputed from f[]*sh0 (-16 VGPR);
// (d) no sched_barrier in fences (rule-18 hazard is asm-ds_read-only;
//     r12 showed order-pinning cost);
// (e) 128-thread blocks, __launch_bounds__(128,2) => compiler must fit
//     2 waves/SIMD (<=256 unified regs); 8 waves/CU target.

#define N_NODES_C 50000
#define N_EDGES_C 300000
#define ALPHA_C 0.20412414523193154f   // 1/sqrt(24)
#define INV_SQRT3_C 0.5773502691896258f
#define BN_EPS_C 1e-5f

typedef unsigned int u32;
typedef unsigned long long u64;
typedef unsigned short u16;
typedef __attribute__((ext_vector_type(8))) short bf16x8;
typedef __attribute__((ext_vector_type(4))) float f32x4;

// workspace layout (float offsets)
#define OFF_STATS 0u            // 40
#define OFF_FLAG  48u           // u32 dtype flag
#define OFF_W3T   64u           // 49152 floats: frag-packed W3 bf16 hi + lo
#define OFF_W1T   49216u        // 512
#define OFF_B1    49728u        // 64
#define OFF_W2T   49792u        // 4096
#define OFF_B2    53888u        // 64
#define OFF_B3    53952u        // 768
#define OFF_SI0   54720u        // 256
#define OFF_SI1   54976u        // 64
#define OFF_AGG   55040u        // 50000*48 = 2,400,000 (svb in-place)
#define REQ_WS_BYTES ((size_t)(55040u + 2400000u) * 4u)
// sorted-path extras
#define OFF_DEG     2455040u    // 50000 ints
#define OFF_START   2505040u    // 50001 ints
#define OFF_CURSOR  2555044u    // 50000 ints
#define OFF_POS     2605044u    // 300000 ints (inverse perm: edge -> sorted slot)
#define OFF_MSG     2905044u    // 300000*48 floats (16B aligned)
#define REQ2_WS_BYTES ((size_t)(2905044u + 14400000u) * 4u)   // ~69.2 MB

__device__ __forceinline__ float bflo(u32 u){ union{u32 i; float f;} c; c.i = u<<16; return c.f; }
__device__ __forceinline__ float bfhi(u32 u){ union{u32 i; float f;} c; c.i = u & 0xffff0000u; return c.f; }
__device__ __forceinline__ float b2f(__hip_bfloat16 b){ return (float)b; }
__device__ __forceinline__ u16 f2bf(float f){
    union{float f; u32 i;} c; c.f = f;
    u32 r = c.i + 0x7fffu + ((c.i>>16)&1u);
    return (u16)(r>>16);
}
__device__ __forceinline__ float sigmoidf_(float x){ return 1.0f/(1.0f+__expf(-x)); }
__device__ __forceinline__ float siluf_(float x){ return x*sigmoidf_(x); }
__device__ __forceinline__ float rdv(const void* p, int idx, bool fm){
    return fm ? ((const float*)p)[idx] : b2f(((const __hip_bfloat16*)p)[idx]);
}
__device__ __forceinline__ float sel4(float a, float b, float c, float d, int q){
    float lo = (q&1) ? b : a;
    float hi = (q&1) ? d : c;
    return (q&2) ? hi : lo;
}
__device__ __forceinline__ float sel8(float a0,float a1,float a2,float a3,
                                      float a4,float a5,float a6,float a7,int q){
    float x0=(q&1)?a1:a0, x1=(q&1)?a3:a2, x2=(q&1)?a5:a4, x3=(q&1)?a7:a6;
    float y0=(q&2)?x1:x0, y1=(q&2)?x3:x2;
    return (q&4)?y1:y0;
}
// per-wave LDS fence: LDS is wave-private; lgkmcnt(0) orders ds_write ->
// ds_read within the wave. "memory" clobber orders surrounding memory ops;
// vmcnt is NOT drained, so global prefetch loads stay in flight across it.
// No sched_barrier: all LDS accesses are compiler-visible (rule-18 hazard
// applies only to inline-asm ds_read), and r12 showed order-pinning cost.
__device__ __forceinline__ void wave_fence(){
    asm volatile("s_waitcnt lgkmcnt(0)" ::: "memory");
}

// ---------------- detect dtype ----------------
__global__ void detect_kernel(const u32* __restrict__ nfw, u32* __restrict__ flagp){
    int t = threadIdx.x;
    u32 w = nfw[t];
    int bad = 0;
    u32 lo = w & 0xffffu, hi = w >> 16;
    u32 elo = (lo >> 7) & 0xffu, ehi = (hi >> 7) & 0xffu;
    if (!(lo == 0u || (elo >= 90u && elo <= 140u))) bad++;
    if (!(hi == 0u || (ehi >= 90u && ehi <= 140u))) bad++;
    for (int off=32; off; off>>=1) bad += __shfl_down(bad, off);
    if (t == 0) flagp[0] = (bad >= 8) ? 1u : 0u;
}

__global__ __launch_bounds__(256) void fill_kernel(u32* __restrict__ p, int n, u32 v){
    int i = blockIdx.x*256 + threadIdx.x;
    if (i < n) p[i] = v;
}

// ---------------- prep ----------------
__global__ __launch_bounds__(256) void prep_kernel(
    const void* __restrict__ W1, const void* __restrict__ b1,
    const void* __restrict__ W2, const void* __restrict__ b2,
    const void* __restrict__ W3, const void* __restrict__ b3,
    const void* __restrict__ si0, const void* __restrict__ si1,
    float* __restrict__ ws)
{
    const bool fm = ((const u32*)(ws + OFF_FLAG))[0] != 0u;
    int i = blockIdx.x*256 + threadIdx.x;
    if (i < 49152){
        int j = i & 7, lane = (i>>3)&63, kh = (i>>9)&1, nt = i>>10;
        int n = lane & 15, qd = lane >> 4;
        int k = kh*32 + qd*8 + j;
        int col = nt*16 + n;
        float v = rdv(W3, k*768 + col, fm);
        u16 hv = f2bf(v);
        float hf = bflo((u32)hv);
        u16 lv = f2bf(v - hf);
        u16* BH = (u16*)(ws + OFF_W3T);
        BH[i] = hv;
        BH[49152 + i] = lv;
        return;
    }
    i -= 49152;
    if (i < 512){ int j=i>>3, t=i&7; ws[OFF_W1T+i] = rdv(W1, t*64+j, fm); return; }
    i -= 512;
    if (i < 64){ ws[OFF_B1+i] = rdv(b1, i, fm); return; }
    i -= 64;
    if (i < 4096){ int j=i>>6, k=i&63; ws[OFF_W2T+i] = rdv(W2, k*64+j, fm); return; }
    i -= 4096;
    if (i < 64){ ws[OFF_B2+i] = rdv(b2, i, fm); return; }
    i -= 64;
    if (i < 768){ ws[OFF_B3+i] = rdv(b3, i, fm); return; }
    i -= 768;
    if (i < 256){ int w=i>>4, u=i&15; ws[OFF_SI0+i] = rdv(si0, u*16+w, fm)*0.25f; return; }
    i -= 256;
    if (i < 64){ int w=i>>3, u=i&7; ws[OFF_SI1+i] = rdv(si1, u*8+w, fm)*0.35355339059327373f; return; }
}

// ---------------- sort: count / scan / pos-scatter ----------------
__global__ __launch_bounds__(256) void count_kernel(const int* __restrict__ dst, int* __restrict__ deg){
    int i = blockIdx.x*256 + threadIdx.x;
    if (i < N_EDGES_C) atomicAdd(&deg[dst[i]], 1);
}

__global__ __launch_bounds__(1024) void scan_kernel(const int* __restrict__ deg,
                                                    int* __restrict__ start,
                                                    int* __restrict__ cursor){
    __shared__ int buf[2][1024];
    const int t = threadIdx.x;
    const int c0 = t*49;
    int local = 0;
    #pragma unroll 1
    for (int i=0;i<49;i++){ int idx=c0+i; if (idx<N_NODES_C) local += deg[idx]; }
    buf[0][t] = local;
    __syncthreads();
    int src=0;
    for (int off=1; off<1024; off<<=1){
        int v = buf[src][t];
        if (t>=off) v += buf[src][t-off];
        buf[src^1][t]=v;
        src^=1;
        __syncthreads();
    }
    int off = (t==0)?0:buf[src][t-1];
    #pragma unroll 1
    for (int i=0;i<49;i++){
        int idx=c0+i;
        if (idx<N_NODES_C){ start[idx]=off; cursor[idx]=off; off+=deg[idx]; }
    }
    if (t==0) start[N_NODES_C]=buf[src][1023];
}

__global__ __launch_bounds__(256) void scatter_kernel(const int* __restrict__ dst,
                                                      int* __restrict__ cursor,
                                                      int* __restrict__ pos){
    int i = blockIdx.x*256 + threadIdx.x;
    if (i < N_EDGES_C){
        pos[i] = atomicAdd(&cursor[dst[i]], 1);
    }
}

// ---------------- edge kernel (2 independent waves / block; per-wave LDS) ----------------
template<bool SORTED>
__global__ __launch_bounds__(128, 2) void edge_kernel_t(
    const void* __restrict__ nfv,
    const void* __restrict__ eshv,
    const void* __restrict__ ebv,
    const int* __restrict__ eidx,
    const float* __restrict__ ws,
    const int* __restrict__ pos,
    float* __restrict__ outbuf)      // SORTED: msg[300K][48] ; else: agg[50K][48]
{
    // Per-wave private 12544B slice. union: h2 region (9216 B) is dead once
    // A-fragments are in registers; tpb (12544 B) overlays it.
    __shared__ __align__(16) char uni[2][12544];
    const int wv   = threadIdx.x >> 6;
    const int lane = threadIdx.x & 63;
    u16   (*h2hi)[72] = (u16 (*)[72])uni[wv];   // [64][72]
    float (*tpb)[49]  = (float (*)[49])uni[wv]; // [64][49]

    const bool fm = ((const u32*)(ws + OFF_FLAG))[0] != 0u;
    const int m    = lane & 15;
    const int quad = lane >> 4;
    const int e    = blockIdx.x*128 + threadIdx.x;
    const bool act = e < N_EDGES_C;
    const int slot = (SORTED && act) ? pos[e] : 0;   // early, coalesced

    // ---- inputs (original order: coalesced; verified rounds 3/8/9) ----
    float sh0=0.f, sh1x=0.f, sh1y=0.f, sh1z=0.f;
    float f[40];
    float bas[8];
    #pragma unroll
    for (int i=0;i<40;i++) f[i]=0.f;
    #pragma unroll
    for (int i=0;i<8;i++) bas[i]=0.f;
    if (act){
        const int src = eidx[e];
        if (!fm){
            const u32* p = (const u32*)((const __hip_bfloat16*)eshv + (size_t)e*4);
            u32 a = p[0], b = p[1];
            sh0 = bflo(a); sh1x = bfhi(a); sh1y = bflo(b); sh1z = bfhi(b);
            const uint4* qq = (const uint4*)((const __hip_bfloat16*)nfv + (size_t)src*40);
            #pragma unroll
            for (int i=0;i<5;i++){
                uint4 r = qq[i];
                f[i*8+0]=bflo(r.x); f[i*8+1]=bfhi(r.x);
                f[i*8+2]=bflo(r.y); f[i*8+3]=bfhi(r.y);
                f[i*8+4]=bflo(r.z); f[i*8+5]=bfhi(r.z);
                f[i*8+6]=bflo(r.w); f[i*8+7]=bfhi(r.w);
            }
            uint4 r = *(const uint4*)((const __hip_bfloat16*)ebv + (size_t)e*8);
            bas[0]=bflo(r.x); bas[1]=bfhi(r.x); bas[2]=bflo(r.y); bas[3]=bfhi(r.y);
            bas[4]=bflo(r.z); bas[5]=bfhi(r.z); bas[6]=bflo(r.w); bas[7]=bfhi(r.w);
        } else {
            float4 r = *(const float4*)((const float*)eshv + (size_t)e*4);
            sh0 = r.x; sh1x = r.y; sh1y = r.z; sh1z = r.w;
            const float4* qq = (const float4*)((const float*)nfv + (size_t)src*40);
            #pragma unroll
            for (int i=0;i<10;i++){
                float4 t = qq[i];
                f[i*4+0]=t.x; f[i*4+1]=t.y; f[i*4+2]=t.z; f[i*4+3]=t.w;
            }
            const float4* qb = (const float4*)((const float*)ebv + (size_t)e*8);
            float4 t0 = qb[0], t1 = qb[1];
            bas[0]=t0.x; bas[1]=t0.y; bas[2]=t0.z; bas[3]=t0.w;
            bas[4]=t1.x; bas[5]=t1.y; bas[6]=t1.z; bas[7]=t1.w;
        }
    }

    // ---- MLP1 ----
    const float* W1T = ws + OFF_W1T;
    const float* b1f = ws + OFF_B1;
    float h1[64];
    #pragma unroll
    for (int j=0;j<64;j++){
        const float* w = W1T + j*8;
        float t0 = b1f[j] + bas[0]*w[0] + bas[4]*w[4];
        float t1 = bas[1]*w[1] + bas[5]*w[5];
        float t2 = bas[2]*w[2] + bas[6]*w[6];
        float t3 = bas[3]*w[3] + bas[7]*w[7];
        h1[j] = siluf_((t0+t1)+(t2+t3));
    }

    // ---- MLP2 -> bf16 h2 rows in LDS (paired u32 writes) ----
    const float* W2T = ws + OFF_W2T;
    const float* bb2 = ws + OFF_B2;
    #pragma unroll 1
    for (int j=0;j<64;j+=2){
        const float* w0 = W2T + j*64;
        const float* w1 = w0 + 64;
        float a0=bb2[j],   a1=0.f, a2=0.f, a3=0.f;
        float c0=bb2[j+1], c1=0.f, c2=0.f, c3=0.f;
        #pragma unroll
        for (int k=0;k<64;k+=4){
            a0 += h1[k]*w0[k];     a1 += h1[k+1]*w0[k+1];
            a2 += h1[k+2]*w0[k+2]; a3 += h1[k+3]*w0[k+3];
            c0 += h1[k]*w1[k];     c1 += h1[k+1]*w1[k+1];
            c2 += h1[k+2]*w1[k+2]; c3 += h1[k+3]*w1[k+3];
        }
        u32 pk = (u32)f2bf(siluf_((a0+a1)+(a2+a3)))
               | ((u32)f2bf(siluf_((c0+c1)+(c2+c3)))<<16);
        *(u32*)&h2hi[lane][j] = pk;
    }
    wave_fence();

    // ---- A fragments (consume all of h2 into registers) ----
    bf16x8 Afr[4][2];
    #pragma unroll
    for (int g=0;g<4;g++){
        Afr[g][0] = *(const bf16x8*)&h2hi[g*16+m][quad*8];
        Afr[g][1] = *(const bf16x8*)&h2hi[g*16+m][32 + quad*8];
    }
    wave_fence();   // h2 region now dead -> tpb may overlay

    // ---- per-thread contraction coefficients ----
    // f[16..39] die here; only f[0..15] + vxsh0 + dvv stay live in the loop.
    float vxsh0[24], dvv[8];
    #pragma unroll
    for (int j=0;j<24;j++) vxsh0[j] = f[16+j]*sh0;
    #pragma unroll
    for (int u=0;u<8;u++)
        dvv[u] = (f[16+u*3]*sh1x + f[17+u*3]*sh1y + f[18+u*3]*sh1z)*INV_SQRT3_C;

    float outs[24], tsv[8], av0[8], av1[8], av2[8];
    #pragma unroll
    for (int t=0;t<24;t++) outs[t]=0.f;
    #pragma unroll
    for (int t=0;t<8;t++){ tsv[t]=0.f; av0[t]=0.f; av1[t]=0.f; av2[t]=0.f; }

    const short* BH = (const short*)(ws + OFF_W3T);
    const short* BL = BH + 49152;
    const float* b3f = ws + OFF_B3;

    auto loadB = [&](bf16x8* dst2, int cc2){
        #pragma unroll
        for (int ntl=0; ntl<3; ntl++){
            const int nt = cc2*3 + ntl;
            dst2[ntl*4+0] = *(const bf16x8*)(BH + ((nt*2+0)*64 + lane)*8);
            dst2[ntl*4+1] = *(const bf16x8*)(BL + ((nt*2+0)*64 + lane)*8);
            dst2[ntl*4+2] = *(const bf16x8*)(BH + ((nt*2+1)*64 + lane)*8);
            dst2[ntl*4+3] = *(const bf16x8*)(BL + ((nt*2+1)*64 + lane)*8);
        }
    };

    bf16x8 Bc[12];
    loadB(Bc, 0);

    #pragma unroll 1
    for (int cc=0; cc<16; cc++){
        // ---- MFMA consumes Bc (compiler inserts vmcnt wait on Bc deps) ----
        #pragma unroll
        for (int ntl=0; ntl<3; ntl++){
            #pragma unroll
            for (int g=0; g<4; g++){
                f32x4 acc = {0.f,0.f,0.f,0.f};
                acc = __builtin_amdgcn_mfma_f32_16x16x32_bf16(Afr[g][0], Bc[ntl*4+0], acc, 0,0,0);
                acc = __builtin_amdgcn_mfma_f32_16x16x32_bf16(Afr[g][0], Bc[ntl*4+1], acc, 0,0,0);
                acc = __builtin_amdgcn_mfma_f32_16x16x32_bf16(Afr[g][1], Bc[ntl*4+2], acc, 0,0,0);
                acc = __builtin_amdgcn_mfma_f32_16x16x32_bf16(Afr[g][1], Bc[ntl*4+3], acc, 0,0,0);
                #pragma unroll
                for (int r=0;r<4;r++) tpb[g*16+quad*4+r][ntl*16+m] = acc[r];
            }
        }
        // Bc registers are dead now: refill for next iteration; the loads
        // stay in flight across the lgkm-only fence and overlap the
        // contraction VALU below (~300 cy) -> L2 latency hidden.
        if (cc < 15) loadB(Bc, cc+1);
        wave_fence();

        float cA=0.f, cB=0.f;
        if (cc < 8){
            cA = sel8(f[0],f[2],f[4],f[6],f[8],f[10],f[12],f[14], cc)*sh0;
            cB = sel8(f[1],f[3],f[5],f[7],f[9],f[11],f[13],f[15], cc)*sh0;
        } else if (cc < 12){
            cA = sel4(dvv[0],dvv[2],dvv[4],dvv[6], cc-8);
            cB = sel4(dvv[1],dvv[3],dvv[5],dvv[7], cc-8);
        }
        const float* b3c = b3f + cc*48;
        float v[16];

        // ---- chunk 0: cols 0..15 ----
        #pragma unroll
        for (int c=0;c<16;c++) v[c] = tpb[lane][c] + b3c[c];
        if (cc < 12){
            #pragma unroll
            for (int c=0;c<16;c++) outs[c] += cA*v[c];
        } else if (cc == 12){
            #pragma unroll
            for (int c=0;c<16;c++) tsv[c&7] += f[c>>3]*v[c];
        } else if (cc == 13){
            #pragma unroll
            for (int c=0;c<16;c++) tsv[c&7] += f[6+(c>>3)]*v[c];
        } else if (cc == 14){
            #pragma unroll
            for (int c=0;c<16;c++) tsv[c&7] += f[12+(c>>3)]*v[c];
        } else {
            #pragma unroll
            for (int c=0;c<16;c++){
                const int u=2+(c>>3), w=c&7;
                av0[w] += vxsh0[u*3+0]*v[c];
                av1[w] += vxsh0[u*3+1]*v[c];
                av2[w] += vxsh0[u*3+2]*v[c];
            }
        }

        // ---- chunk 1: cols 16..31 ----
        #pragma unroll
        for (int c=0;c<16;c++) v[c] = tpb[lane][16+c] + b3c[16+c];
        if (cc < 12){
            #pragma unroll
            for (int c=0;c<8;c++)  outs[16+c] += cA*v[c];
            #pragma unroll
            for (int c=8;c<16;c++) outs[c-8]  += cB*v[c];
        } else if (cc == 12){
            #pragma unroll
            for (int c=0;c<16;c++) tsv[c&7] += f[2+(c>>3)]*v[c];
        } else if (cc == 13){
            #pragma unroll
            for (int c=0;c<16;c++) tsv[c&7] += f[8+(c>>3)]*v[c];
        } else if (cc == 14){
            #pragma unroll
            for (int c=0;c<16;c++) tsv[c&7] += f[14+(c>>3)]*v[c];
        } else {
            #pragma unroll
            for (int c=0;c<16;c++){
                const int u=4+(c>>3), w=c&7;
                av0[w] += vxsh0[u*3+0]*v[c];
                av1[w] += vxsh0[u*3+1]*v[c];
                av2[w] += vxsh0[u*3+2]*v[c];
            }
        }

        // ---- chunk 2: cols 32..47 ----
        #pragma unroll
        for (int c=0;c<16;c++) v[c] = tpb[lane][32+c] + b3c[32+c];
        if (cc < 12){
            #pragma unroll
            for (int c=0;c<16;c++) outs[8+c] += cB*v[c];
        } else if (cc == 12){
            #pragma unroll
            for (int c=0;c<16;c++) tsv[c&7] += f[4+(c>>3)]*v[c];
        } else if (cc == 13){
            #pragma unroll
            for (int c=0;c<16;c++) tsv[c&7] += f[10+(c>>3)]*v[c];
        } else if (cc == 14){
            #pragma unroll
            for (int c=0;c<16;c++){
                const int u=(c>>3), w=c&7;
                av0[w] += vxsh0[u*3+0]*v[c];
                av1[w] += vxsh0[u*3+1]*v[c];
                av2[w] += vxsh0[u*3+2]*v[c];
            }
        } else {
            #pragma unroll
            for (int c=0;c<16;c++){
                const int u=6+(c>>3), w=c&7;
                av0[w] += vxsh0[u*3+0]*v[c];
                av1[w] += vxsh0[u*3+1]*v[c];
                av2[w] += vxsh0[u*3+2]*v[c];
            }
        }
        wave_fence();   // vals reads done before next iteration's tpb stores
    }

    if (act){
        if (SORTED){
            // scattered full-line stores to msg[slot][48]
            float v48[48];
            #pragma unroll
            for (int w=0;w<24;w++) v48[w] = outs[w]*ALPHA_C;
            #pragma unroll
            for (int w=0;w<8;w++){
                v48[24+w*3+0] = (tsv[w]*sh1x + av0[w])*ALPHA_C;
                v48[24+w*3+1] = (tsv[w]*sh1y + av1[w])*ALPHA_C;
                v48[24+w*3+2] = (tsv[w]*sh1z + av2[w])*ALPHA_C;
            }
            float4* mp = (float4*)(outbuf + (size_t)slot*48);
            #pragma unroll
            for (int q=0;q<12;q++) mp[q] = make_float4(v48[q*4],v48[q*4+1],v48[q*4+2],v48[q*4+3]);
        } else {
            const int dst = eidx[N_EDGES_C + e];
            float* dp = outbuf + (size_t)dst*48;
            #pragma unroll
            for (int w=0;w<24;w++) atomicAdd(dp+w, outs[w]*ALPHA_C);
            #pragma unroll
            for (int w=0;w<8;w++){
                atomicAdd(dp+24+w*3+0, (tsv[w]*sh1x + av0[w])*ALPHA_C);
                atomicAdd(dp+24+w*3+1, (tsv[w]*sh1y + av1[w])*ALPHA_C);
                atomicAdd(dp+24+w*3+2, (tsv[w]*sh1z + av2[w])*ALPHA_C);
            }
        }
    }
}

// ---------------- node kernel (templated source of agg) ----------------
template<bool SORTED>
__global__ __launch_bounds__(256) void node_kernel_t(
    const float* __restrict__ ws,
    const float* __restrict__ msg,     // SORTED only
    const int* __restrict__ start,     // SORTED only
    float* __restrict__ svb,           // agg region: read (atomic path) / write svb
    float* __restrict__ stats)
{
    const float* si0T = ws + OFF_SI0;
    const float* si1T = ws + OFF_SI1;
    const int n = blockIdx.x*256 + threadIdx.x;
    const bool act = n < N_NODES_C;

    float a[48];
    #pragma unroll
    for (int j=0;j<48;j++) a[j]=0.f;
    if (act){
        if (SORTED){
            int s = start[n], en = start[n+1];
            #pragma unroll 1
            for (int r=s; r<en; ++r){
                const float4* mp = (const float4*)(msg + (size_t)r*48);
                #pragma unroll
                for (int q=0;q<12;q++){
                    float4 t = mp[q];
                    a[q*4]+=t.x; a[q*4+1]+=t.y; a[q*4+2]+=t.z; a[q*4+3]+=t.w;
                }
            }
        } else {
            const float4* p = (const float4*)(svb + (size_t)n*48);
            #pragma unroll
            for (int q=0;q<12;q++){ float4 r=p[q]; a[q*4]=r.x; a[q*4+1]=r.y; a[q*4+2]=r.z; a[q*4+3]=r.w; }
        }
    }
    float spre[16];
    #pragma unroll
    for (int u=0;u<16;u++) spre[u]=siluf_(a[u]);
    float v[24];
    #pragma unroll
    for (int u=0;u<8;u++){
        float g = sigmoidf_(a[16+u]);
        v[u*3+0]=a[24+u*3+0]*g; v[u*3+1]=a[24+u*3+1]*g; v[u*3+2]=a[24+u*3+2]*g;
    }
    float so[16];
    #pragma unroll
    for (int w=0;w<16;w++){
        const float* c = si0T + w*16;
        float t0=0.f,t1=0.f,t2=0.f,t3=0.f;
        #pragma unroll
        for (int u=0;u<16;u+=4){ t0+=spre[u]*c[u]; t1+=spre[u+1]*c[u+1]; t2+=spre[u+2]*c[u+2]; t3+=spre[u+3]*c[u+3]; }
        so[w]=(t0+t1)+(t2+t3);
    }
    float vo[24];
    #pragma unroll
    for (int w=0;w<8;w++){
        const float* c = si1T + w*8;
        float a0=0.f,a1=0.f,a2=0.f;
        #pragma unroll
        for (int u=0;u<8;u++){ a0+=v[u*3]*c[u]; a1+=v[u*3+1]*c[u]; a2+=v[u*3+2]*c[u]; }
        vo[w*3]=a0; vo[w*3+1]=a1; vo[w*3+2]=a2;
    }
    if (act){
        float4* op = (float4*)(svb + (size_t)n*48);
        op[0]=make_float4(so[0],so[1],so[2],so[3]);
        op[1]=make_float4(so[4],so[5],so[6],so[7]);
        op[2]=make_float4(so[8],so[9],so[10],so[11]);
        op[3]=make_float4(so[12],so[13],so[14],so[15]);
        #pragma unroll
        for (int q=0;q<6;q++) op[4+q]=make_float4(vo[q*4],vo[q*4+1],vo[q*4+2],vo[q*4+3]);
    }
    float r[40];
    #pragma unroll
    for (int w=0;w<16;w++){ r[w]=so[w]; r[16+w]=so[w]*so[w]; }
    #pragma unroll
    for (int w=0;w<8;w++) r[32+w]=(vo[w*3]*vo[w*3]+vo[w*3+1]*vo[w*3+1]+vo[w*3+2]*vo[w*3+2])*(1.0f/3.0f);
    #pragma unroll
    for (int j=0;j<40;j++){
        float x = r[j];
        for (int off=32; off; off>>=1) x += __shfl_down(x, off);
        r[j]=x;
    }
    if ((threadIdx.x & 63)==0){
        #pragma unroll
        for (int j=0;j<40;j++) atomicAdd(stats+j, r[j]);
    }
}

// ---------------- finalize ----------------
__global__ __launch_bounds__(256) void final_kernel(
    const float* __restrict__ ws, const float* __restrict__ svb,
    const void* __restrict__ nfv,
    const void* __restrict__ bnws, const void* __restrict__ bnbs,
    const void* __restrict__ bnwv,
    void* __restrict__ outv)
{
    const float* stats = ws + OFF_STATS;
    const bool fm = ((const u32*)(ws + OFF_FLAG))[0] != 0u;
    const int n = blockIdx.x*256 + threadIdx.x;
    if (n >= N_NODES_C) return;
    const float invN = 1.0f/(float)N_NODES_C;
    const float* s = svb + (size_t)n*48;
    float nfr[40];
    if (!fm){
        const uint4* q = (const uint4*)((const __hip_bfloat16*)nfv + (size_t)n*40);
        #pragma unroll
        for (int i=0;i<5;i++){
            uint4 r = q[i];
            nfr[i*8+0]=bflo(r.x); nfr[i*8+1]=bfhi(r.x);
            nfr[i*8+2]=bflo(r.y); nfr[i*8+3]=bfhi(r.y);
            nfr[i*8+4]=bflo(r.z); nfr[i*8+5]=bfhi(r.z);
            nfr[i*8+6]=bflo(r.w); nfr[i*8+7]=bfhi(r.w);
        }
    } else {
        const float4* q = (const float4*)((const float*)nfv + (size_t)n*40);
        #pragma unroll
        for (int i=0;i<10;i++){
            float4 t = q[i];
            nfr[i*4+0]=t.x; nfr[i*4+1]=t.y; nfr[i*4+2]=t.z; nfr[i*4+3]=t.w;
        }
    }
    float vals[40];
    #pragma unroll
    for (int w=0;w<16;w++){
        float mean = stats[w]*invN;
        float var  = fmaxf(stats[16+w]*invN - mean*mean, 0.0f);
        float is   = rsqrtf(var + BN_EPS_C) * rdv(bnws, w, fm);
        vals[w] = (s[w]-mean)*is + rdv(bnbs, w, fm) + nfr[w];
    }
    #pragma unroll
    for (int w=0;w<8;w++){
        float iv = rsqrtf(fmaxf(stats[32+w]*invN, 0.0f) + BN_EPS_C) * rdv(bnwv, w, fm);
        vals[16+w*3+0] = s[16+w*3+0]*iv + nfr[16+w*3+0];
        vals[16+w*3+1] = s[16+w*3+1]*iv + nfr[16+w*3+1];
        vals[16+w*3+2] = s[16+w*3+2]*iv + nfr[16+w*3+2];
    }
    if (!fm){
        u32 packed[20];
        #pragma unroll
        for (int q=0;q<20;q++) packed[q] = (u32)f2bf(vals[2*q]) | ((u32)f2bf(vals[2*q+1])<<16);
        uint4* op = (uint4*)((u16*)outv + (size_t)n*40);
        #pragma unroll
        for (int q=0;q<5;q++) op[q] = make_uint4(packed[q*4],packed[q*4+1],packed[q*4+2],packed[q*4+3]);
    } else {
        float4* op = (float4*)((float*)outv + (size_t)n*40);
        #pragma unroll
        for (int q=0;q<10;q++) op[q] = make_float4(vals[q*4],vals[q*4+1],vals[q*4+2],vals[q*4+3]);
    }
}

extern "C" void kernel_launch(void* const* d_in, const int* in_sizes, int n_in,
                              void* d_out, int out_size, void* d_ws, size_t ws_size,
                              hipStream_t stream)
{
    const void* nf     = d_in[0];
    const void* esh    = d_in[1];
    const void* ebasis = d_in[2];
    const int*  eidx   = (const int*)d_in[3];
    const void* W1 = d_in[4];
    const void* b1 = d_in[5];
    const void* W2 = d_in[6];
    const void* b2 = d_in[7];
    const void* W3 = d_in[8];
    const void* b3 = d_in[9];
    const void* si0 = d_in[10];
    const void* si1 = d_in[11];
    const void* bnws = d_in[12];
    const void* bnbs = d_in[13];
    const void* bnwv = d_in[14];

    float* ws    = (float*)d_ws;
    float* stats = ws + OFF_STATS;
    float* agg   = ws + OFF_AGG;

    if (ws_size < REQ_WS_BYTES){
        int nw = out_size/2;
        fill_kernel<<<(nw+255)/256, 256, 0, stream>>>((u32*)d_out, nw, 0x447A447Au);
        return;
    }

    const int* dst = eidx + N_EDGES_C;
    const int EB = (N_EDGES_C+255)/256;
    const int EB128 = (N_EDGES_C+127)/128;

    hipMemsetAsync(stats, 0, 48*sizeof(float), stream);
    detect_kernel<<<1, 64, 0, stream>>>((const u32*)nf, (u32*)(ws + OFF_FLAG));
    prep_kernel<<<215, 256, 0, stream>>>(W1,b1,W2,b2,W3,b3,si0,si1, ws);

    if (ws_size >= REQ2_WS_BYTES){
        // ---- sorted (atomic-free aggregation) path ----
        int*   deg    = (int*)(ws + OFF_DEG);
        int*   startp = (int*)(ws + OFF_START);
        int*   cursor = (int*)(ws + OFF_CURSOR);
        int*   pos    = (int*)(ws + OFF_POS);
        float* msg    = ws + OFF_MSG;

        hipMemsetAsync(deg, 0, N_NODES_C*sizeof(int), stream);
        count_kernel<<<EB, 256, 0, stream>>>(dst, deg);
        scan_kernel<<<1, 1024, 0, stream>>>(deg, startp, cursor);
        scatter_kernel<<<EB, 256, 0, stream>>>(dst, cursor, pos);
        edge_kernel_t<true><<<EB128, 128, 0, stream>>>(nf, esh, ebasis, eidx, ws, pos, msg);
        node_kernel_t<true><<<(N_NODES_C+255)/256, 256, 0, stream>>>(ws, msg, startp, agg, stats);
    } else {
        // ---- fallback: atomic path ----
        hipMemsetAsync(agg, 0, (size_t)2400000*sizeof(float), stream);
        edge_kernel_t<false><<<EB128, 128, 0, stream>>>(nf, esh, ebasis, eidx, ws, nullptr, agg);
        node_kernel_t<false><<<(N_NODES_C+255)/256, 256, 0, stream>>>(ws, nullptr, nullptr, agg, stats);
    }
    final_kernel<<<(N_NODES_C+255)/256, 256, 0, stream>>>(ws, agg, nf, bnws, bnbs, bnwv, d_out);
}